// Round 9
// baseline (420.316 us; speedup 1.0000x reference)
//
#include <hip/hip_runtime.h>
#include <hip/hip_bf16.h>

#define B_  2
#define S_  2048
#define D_  2048
#define H_  16
#define DK_ 128
#define M_  (B_*S_)   // 4096

typedef unsigned short u16;
typedef short bf16x8 __attribute__((ext_vector_type(8)));
typedef float f32x4  __attribute__((ext_vector_type(4)));

#define NEG_BIG (-1.0e30f)

// round-to-nearest-even fp32 -> bf16 (finite inputs)
__device__ __forceinline__ u16 f2bf(float f){
    unsigned int u = __float_as_uint(f);
    unsigned int r = (u + 0x7fffu + ((u >> 16) & 1u)) >> 16;
    return (u16)r;
}

// load 8 consecutive f32, convert to 8 bf16 packed in a uint4
__device__ __forceinline__ uint4 cvt8(const float* p){
    float4 a = *(const float4*)p;
    float4 b = *(const float4*)(p + 4);
    uint4 r;
    r.x = ((unsigned int)f2bf(a.y) << 16) | (unsigned int)f2bf(a.x);
    r.y = ((unsigned int)f2bf(a.w) << 16) | (unsigned int)f2bf(a.z);
    r.z = ((unsigned int)f2bf(b.y) << 16) | (unsigned int)f2bf(b.x);
    r.w = ((unsigned int)f2bf(b.w) << 16) | (unsigned int)f2bf(b.z);
    return r;
}

// unpack 8 bf16 (uint4) -> 8 f32
__device__ __forceinline__ void unpack8(const uint4 v, float* f){
    f[0]=__uint_as_float(v.x<<16); f[1]=__uint_as_float(v.x&0xffff0000u);
    f[2]=__uint_as_float(v.y<<16); f[3]=__uint_as_float(v.y&0xffff0000u);
    f[4]=__uint_as_float(v.z<<16); f[5]=__uint_as_float(v.z&0xffff0000u);
    f[6]=__uint_as_float(v.w<<16); f[7]=__uint_as_float(v.w&0xffff0000u);
}

// async 16B global -> LDS (gfx950). LDS dest must be wave-uniform base + lane*16.
__device__ __forceinline__ void async16(const void* g, void* l){
    __builtin_amdgcn_global_load_lds(
        (const __attribute__((address_space(1))) void*)g,
        (__attribute__((address_space(3))) void*)l, 16, 0, 0);
}

// ---------------- one-shot f32 -> bf16 conversion of all inputs ----------------
__global__ __launch_bounds__(256) void cvt_all(
    const float* __restrict__ x,  const float* __restrict__ wq, const float* __restrict__ wk,
    const float* __restrict__ wv, const float* __restrict__ wo,
    u16* __restrict__ xb, u16* __restrict__ wqb, u16* __restrict__ wkb,
    u16* __restrict__ wvb, u16* __restrict__ wob)
{
    int c = blockIdx.x*256 + threadIdx.x;
    const float* src; u16* dst; int lc;
    if      (c < 1048576){ src = x;  dst = xb;  lc = c; }
    else if (c < 1572864){ src = wq; dst = wqb; lc = c - 1048576; }
    else if (c < 2097152){ src = wk; dst = wkb; lc = c - 1572864; }
    else if (c < 2621440){ src = wv; dst = wvb; lc = c - 2097152; }
    else                 { src = wo; dst = wob; lc = c - 2621440; }
    *(uint4*)&dst[(size_t)lc*8] = cvt8(&src[(size_t)lc*8]);
}

// ---------------- 256^2 4-phase bf16 GEMM for QK-proj (round-8 validated) ----------------
// + round-9: RoPE fused into the epilogue (rotation partner kk^1 lives in lane
// l15^1 -> one shfl_xor + sincos per element; Q pre-scaled by log2(e)/sqrt(dk)
// for exp2-domain softmax). Removes the separate rope kernel + its launch gap.
__global__ __launch_bounds__(512, 2) void gemm4ph(
    const u16* __restrict__ A, const u16* __restrict__ W0, const u16* __restrict__ W1,
    u16* __restrict__ C0, u16* __restrict__ C1)
{
    __shared__ __align__(16) u16 Ab[2][256*64];   // [buf][row][col], XOR-chunk phys layout
    __shared__ __align__(16) u16 Bb[2][256*64];

    const int tid  = threadIdx.x;
    const int lane = tid & 63;
    const int w    = tid >> 6;
    const int quad = lane >> 4;
    const int l15  = lane & 15;
    const int wM   = w & 1;           // A-half this wave consumes
    const int wN   = w >> 1;          // 0..3 (n-quarter)
    const int bH   = w >> 2;          // B-half this wave consumes
    const int cw   = w >> 1;          // coop index among same-wM waves (0..3)
    const int cb   = w & 3;           // coop index among same-bH waves (0..3)
    const int sw   = l15 & 7;
    const int blockN = blockIdx.x * 256;
    const int blockM = blockIdx.y * 256;

    const u16* Wm = blockIdx.z ? W1 : W0;
    u16*       Cm = blockIdx.z ? C1 : C0;

    f32x4 acc[32];                    // [mi 0..7][ni 0..3]
    #pragma unroll
    for (int i = 0; i < 32; ++i) acc[i] = (f32x4){0.f,0.f,0.f,0.f};

    // stage load l (0..3) of my A-half of tile t into Ab[t&1]
    auto stageA = [&](int t, int l){
        int c  = l*256 + cw*64 + lane;        // chunk in half, rows in consumption order
        int ra = c >> 3, g = c & 7;
        int cl = g ^ (ra & 7);                // inverse XOR swizzle on global source
        int kb = t*64 + cl*8;
        async16(&A[(size_t)(blockM + wM*128 + ra)*2048 + kb],
                &Ab[t & 1][wM*8192 + c*8]);
    };
    auto stageB = [&](int t, int l){
        int c  = l*256 + cb*64 + lane;
        int rb = c >> 3, g = c & 7;
        int cl = g ^ (rb & 7);
        int kb = t*64 + cl*8;
        async16(&Wm[(size_t)(blockN + bH*128 + rb)*2048 + kb],
                &Bb[t & 1][bH*8192 + c*8]);
    };

    // prologue: B(0) then A(0); retire B(0)+A(0)rows0-63 (first 6), leave A(0) tail
    stageB(0,0); stageB(0,1); stageB(0,2); stageB(0,3);
    stageA(0,0); stageA(0,1); stageA(0,2); stageA(0,3);
    asm volatile("s_waitcnt vmcnt(2)" ::: "memory");
    __builtin_amdgcn_s_barrier();
    __builtin_amdgcn_sched_barrier(0);

    for (int t = 0; t < 32; ++t){
        const u16* ab = &Ab[t & 1][0];
        const u16* bb = &Bb[t & 1][0];
        const bool st = (t < 31);
        bf16x8 bfv[4][2], af[2][2];

        // ---- phase 0: mi 0,1 (+ load all B-frags into regs) ----
        #pragma unroll
        for (int ni = 0; ni < 4; ++ni)
            #pragma unroll
            for (int kk = 0; kk < 2; ++kk)
                bfv[ni][kk] = *(const bf16x8*)&bb[(wN*64 + ni*16 + l15)*64 + (((kk*4+quad) ^ sw))*8];
        #pragma unroll
        for (int j = 0; j < 2; ++j)
            #pragma unroll
            for (int kk = 0; kk < 2; ++kk)
                af[j][kk] = *(const bf16x8*)&ab[(wM*128 + (0+j)*16 + l15)*64 + (((kk*4+quad) ^ sw))*8];
        if (st){ stageB(t+1, 0); stageB(t+1, 1); }
        __builtin_amdgcn_s_barrier();
        asm volatile("s_waitcnt lgkmcnt(0)" ::: "memory");
        __builtin_amdgcn_sched_barrier(0);
        __builtin_amdgcn_s_setprio(1);
        #pragma unroll
        for (int j = 0; j < 2; ++j)
            #pragma unroll
            for (int ni = 0; ni < 4; ++ni)
                #pragma unroll
                for (int kk = 0; kk < 2; ++kk)
                    acc[(0+j)*4 + ni] = __builtin_amdgcn_mfma_f32_16x16x32_bf16(
                        af[j][kk], bfv[ni][kk], acc[(0+j)*4 + ni], 0, 0, 0);
        __builtin_amdgcn_s_setprio(0);
        __builtin_amdgcn_s_barrier();
        __builtin_amdgcn_sched_barrier(0);

        // ---- phase 1: mi 2,3 ----
        #pragma unroll
        for (int j = 0; j < 2; ++j)
            #pragma unroll
            for (int kk = 0; kk < 2; ++kk)
                af[j][kk] = *(const bf16x8*)&ab[(wM*128 + (2+j)*16 + l15)*64 + (((kk*4+quad) ^ sw))*8];
        if (st){ stageB(t+1, 2); stageB(t+1, 3); }
        __builtin_amdgcn_s_barrier();
        asm volatile("s_waitcnt lgkmcnt(0)" ::: "memory");
        __builtin_amdgcn_sched_barrier(0);
        __builtin_amdgcn_s_setprio(1);
        #pragma unroll
        for (int j = 0; j < 2; ++j)
            #pragma unroll
            for (int ni = 0; ni < 4; ++ni)
                #pragma unroll
                for (int kk = 0; kk < 2; ++kk)
                    acc[(2+j)*4 + ni] = __builtin_amdgcn_mfma_f32_16x16x32_bf16(
                        af[j][kk], bfv[ni][kk], acc[(2+j)*4 + ni], 0, 0, 0);
        __builtin_amdgcn_s_setprio(0);
        if (st) { asm volatile("s_waitcnt vmcnt(4)" ::: "memory"); }   // A(t) rows 64-127 land
        else    { asm volatile("s_waitcnt vmcnt(0)" ::: "memory"); }
        __builtin_amdgcn_s_barrier();
        __builtin_amdgcn_sched_barrier(0);

        // ---- phase 2: mi 4,5 ----
        #pragma unroll
        for (int j = 0; j < 2; ++j)
            #pragma unroll
            for (int kk = 0; kk < 2; ++kk)
                af[j][kk] = *(const bf16x8*)&ab[(wM*128 + (4+j)*16 + l15)*64 + (((kk*4+quad) ^ sw))*8];
        if (st){ stageA(t+1, 0); stageA(t+1, 1); }
        __builtin_amdgcn_s_barrier();
        asm volatile("s_waitcnt lgkmcnt(0)" ::: "memory");
        __builtin_amdgcn_sched_barrier(0);
        __builtin_amdgcn_s_setprio(1);
        #pragma unroll
        for (int j = 0; j < 2; ++j)
            #pragma unroll
            for (int ni = 0; ni < 4; ++ni)
                #pragma unroll
                for (int kk = 0; kk < 2; ++kk)
                    acc[(4+j)*4 + ni] = __builtin_amdgcn_mfma_f32_16x16x32_bf16(
                        af[j][kk], bfv[ni][kk], acc[(4+j)*4 + ni], 0, 0, 0);
        __builtin_amdgcn_s_setprio(0);
        __builtin_amdgcn_s_barrier();
        __builtin_amdgcn_sched_barrier(0);

        // ---- phase 3: mi 6,7 ----
        #pragma unroll
        for (int j = 0; j < 2; ++j)
            #pragma unroll
            for (int kk = 0; kk < 2; ++kk)
                af[j][kk] = *(const bf16x8*)&ab[(wM*128 + (6+j)*16 + l15)*64 + (((kk*4+quad) ^ sw))*8];
        if (st){ stageA(t+1, 2); stageA(t+1, 3); }
        __builtin_amdgcn_s_barrier();
        asm volatile("s_waitcnt lgkmcnt(0)" ::: "memory");
        __builtin_amdgcn_sched_barrier(0);
        __builtin_amdgcn_s_setprio(1);
        #pragma unroll
        for (int j = 0; j < 2; ++j)
            #pragma unroll
            for (int ni = 0; ni < 4; ++ni)
                #pragma unroll
                for (int kk = 0; kk < 2; ++kk)
                    acc[(6+j)*4 + ni] = __builtin_amdgcn_mfma_f32_16x16x32_bf16(
                        af[j][kk], bfv[ni][kk], acc[(6+j)*4 + ni], 0, 0, 0);
        __builtin_amdgcn_s_setprio(0);
        if (st) { asm volatile("s_waitcnt vmcnt(2)" ::: "memory"); }   // B(t+1)+A(t+1)head land
        __builtin_amdgcn_s_barrier();
        __builtin_amdgcn_sched_barrier(0);
    }

    // epilogue: fused interleaved-pair RoPE + write C [b][h][s][dk].
    // Pair partner kk^1 is in lane l15^1 (same quad/ni/r). Q (z=0) pre-scaled.
    const float osc  = blockIdx.z ? 1.0f : 0.12751743f;   // log2(e)/sqrt(128)
    const float nl2t = -13.287712379549449f / 64.0f;      // -log2(10000)/64
    #pragma unroll
    for (int mi = 0; mi < 8; ++mi){
        #pragma unroll
        for (int ni = 0; ni < 4; ++ni){
            #pragma unroll
            for (int r = 0; r < 4; ++r){
                float v = acc[mi*4 + ni][r];
                int row = blockM + wM*128 + mi*16 + quad*4 + r;
                int col = blockN + wN*64 + ni*16 + l15;
                float pv = __shfl_xor(v, 1, 64);          // partner kk^1
                int ii = (col >> 1) & 63;                 // rotary pair index
                float inv = exp2f((float)ii * nl2t);
                float ang = (float)(row & 2047) * inv;
                float sn, cn; __sincosf(ang, &sn, &cn);
                float rv = ((col & 1) ? (v*cn + pv*sn) : (v*cn - pv*sn)) * osc;
                int b = row >> 11, s2 = row & 2047;
                int h = col >> 7,  kk = col & 127;
                Cm[(((size_t)(b*H_ + h))*S_ + s2)*DK_ + kk] = f2bf(rv);
            }
        }
    }
}

// ---------------- 256xBN 4-slot-ring bf16 GEMM (round-6 validated) ----------------
template<int MODE, int NF>
__global__ __launch_bounds__(512, 2) void gemm256(
    const u16* __restrict__ A, const u16* __restrict__ W0, const u16* __restrict__ W1,
    void* __restrict__ C0, void* __restrict__ C1)
{
    constexpr int BN = NF * 64;
    __shared__ __align__(16) u16 ring[4][(256 + BN) * 32];

    const int tid  = threadIdx.x;
    const int lane = tid & 63;
    const int w    = tid >> 6;
    const int quad = lane >> 4;
    const int l15  = lane & 15;
    const int wM   = w & 1;
    const int wN   = w >> 1;
    const int blockN = blockIdx.x * BN;
    const int blockM = blockIdx.y * 256;

    const u16* Wm; void* Cm;
    if (MODE == 0){ Wm = blockIdx.z ? W1 : W0; Cm = blockIdx.z ? (void*)C1 : (void*)C0; }
    else          { Wm = W0; Cm = C0; }

    const int cswz = quad ^ ((l15 >> 1) & 3);

    f32x4 acc[8 * NF];
    #pragma unroll
    for (int i = 0; i < 8 * NF; ++i) acc[i] = (f32x4){0.f,0.f,0.f,0.f};

    auto stage = [&](int t){
        const int k0 = t * 32;
        u16* la = (u16*)&ring[t & 3][0];
        u16* lb = la + 256*32;
        #pragma unroll
        for (int it = 0; it < 2; ++it){
            int cc  = it*512 + tid;
            int row = cc >> 2;
            int g   = (cc & 3) ^ ((cc >> 3) & 3);
            int kb  = k0 + g*8;
            const u16* ga;
            if (MODE == 1){
                int rg = blockM + row;
                int b = rg >> 11, s2 = rg & 2047;
                int h = kb >> 7,  kk = kb & 127;
                ga = &A[(((size_t)(b*H_ + h))*S_ + s2)*DK_ + kk];
            } else {
                ga = &A[(size_t)(blockM + row)*2048 + kb];
            }
            async16(ga, la + cc*8);
        }
        #pragma unroll
        for (int it = 0; it < BN/128; ++it){
            int cc  = it*512 + tid;
            int row = cc >> 2;
            int g   = (cc & 3) ^ ((cc >> 3) & 3);
            int kb  = k0 + g*8;
            async16(&Wm[(size_t)(blockN + row)*2048 + kb], lb + cc*8);
        }
    };

    stage(0); stage(1); stage(2);
    if constexpr (NF == 4) asm volatile("s_waitcnt vmcnt(8)" ::: "memory");
    else                   asm volatile("s_waitcnt vmcnt(6)" ::: "memory");
    __builtin_amdgcn_s_barrier();
    __builtin_amdgcn_sched_barrier(0);

    for (int t = 0; t < 64; ++t){
        const u16* la = (const u16*)&ring[t & 3][0];
        const u16* lb = la + 256*32;

        if (t <= 60) stage(t + 3);

        bf16x8 bfv[NF];
        #pragma unroll
        for (int ni = 0; ni < NF; ++ni)
            bfv[ni] = *(const bf16x8*)&lb[(wN*(NF*16) + ni*16 + l15)*32 + cswz*8];

        #pragma unroll
        for (int hf = 0; hf < 2; ++hf){
            bf16x8 af[4];
            #pragma unroll
            for (int mi = 0; mi < 4; ++mi)
                af[mi] = *(const bf16x8*)&la[(wM*128 + hf*64 + mi*16 + l15)*32 + cswz*8];
            __builtin_amdgcn_s_setprio(1);
            #pragma unroll
            for (int mi = 0; mi < 4; ++mi)
                #pragma unroll
                for (int ni = 0; ni < NF; ++ni)
                    acc[(hf*4 + mi)*NF + ni] = __builtin_amdgcn_mfma_f32_16x16x32_bf16(
                        af[mi], bfv[ni], acc[(hf*4 + mi)*NF + ni], 0, 0, 0);
            __builtin_amdgcn_s_setprio(0);
        }

        if constexpr (NF == 4){
            if (t <= 60)      { asm volatile("s_waitcnt vmcnt(8)" ::: "memory"); }
            else if (t == 61) { asm volatile("s_waitcnt vmcnt(4)" ::: "memory"); }
            else if (t == 62) { asm volatile("s_waitcnt vmcnt(0)" ::: "memory"); }
        } else {
            if (t <= 60)      { asm volatile("s_waitcnt vmcnt(6)" ::: "memory"); }
            else if (t == 61) { asm volatile("s_waitcnt vmcnt(3)" ::: "memory"); }
            else if (t == 62) { asm volatile("s_waitcnt vmcnt(0)" ::: "memory"); }
        }
        __builtin_amdgcn_s_barrier();
        __builtin_amdgcn_sched_barrier(0);
    }

    #pragma unroll
    for (int hf = 0; hf < 2; ++hf){
        #pragma unroll
        for (int mi = 0; mi < 4; ++mi){
            #pragma unroll
            for (int ni = 0; ni < NF; ++ni){
                #pragma unroll
                for (int r = 0; r < 4; ++r){
                    float v = acc[(hf*4 + mi)*NF + ni][r];
                    int row = blockM + wM*128 + hf*64 + mi*16 + quad*4 + r;
                    int col = blockN + wN*(NF*16) + ni*16 + l15;
                    if (MODE == 0){
                        int b = row >> 11, s2 = row & 2047;
                        int h = col >> 7,  kk = col & 127;
                        ((u16*)Cm)[(((size_t)(b*H_ + h))*S_ + s2)*DK_ + kk] = f2bf(v);
                    } else if (MODE == 2){
                        int h = row >> 7,  kk = row & 127;
                        int b = col >> 11, s2 = col & 2047;
                        ((u16*)Cm)[(((size_t)(b*H_ + h))*DK_ + kk)*S_ + s2] = f2bf(v);
                    } else {
                        ((float*)Cm)[(size_t)row*2048 + col] = v;
                    }
                }
            }
        }
    }
}

// ---------------- fallback mixed GEMM (round-4, validated) ----------------
template<int MODE>
__global__ __launch_bounds__(256) void gemm_bt(
    const void* __restrict__ Av,
    const float* __restrict__ W0, const float* __restrict__ W1,
    void* __restrict__ C0, void* __restrict__ C1)
{
    __shared__ u16 As[128*40];
    __shared__ u16 Bs[128*40];

    const int tid  = threadIdx.x;
    const int lane = tid & 63;
    const int w    = tid >> 6;
    const int quad = lane >> 4;
    const int l15  = lane & 15;
    const int blockN = blockIdx.x * 128;
    const int blockM = blockIdx.y * 128;

    const float* Wm; void* Cm;
    if (MODE == 0){ Wm = blockIdx.z ? W1 : W0; Cm = blockIdx.z ? (void*)C1 : (void*)C0; }
    else          { Wm = W0; Cm = C0; }

    const int waveM = (w & 1) * 64;
    const int waveN = (w >> 1) * 64;

    f32x4 acc[16];
    #pragma unroll
    for (int i = 0; i < 16; ++i) acc[i] = (f32x4){0.f,0.f,0.f,0.f};

    for (int k0 = 0; k0 < 2048; k0 += 32){
        __syncthreads();
        #pragma unroll
        for (int it = 0; it < 2; ++it){
            int cc  = tid + it*256;
            int row = cc >> 2;
            int ch  = cc & 3;
            int kb  = k0 + ch*8;
            uint4 va;
            if (MODE == 1){
                int g = blockM + row;
                int b = g >> 11, s2 = g & 2047;
                int h = kb >> 7, kk = kb & 127;
                va = *(const uint4*)&((const u16*)Av)[(((size_t)(b*H_ + h))*S_ + s2)*DK_ + kk];
            } else {
                va = cvt8(&((const float*)Av)[(size_t)(blockM+row)*2048 + kb]);
            }
            uint4 vb = cvt8(&Wm[(size_t)(blockN+row)*2048 + kb]);
            *(uint4*)&As[row*40 + ch*8] = va;
            *(uint4*)&Bs[row*40 + ch*8] = vb;
        }
        __syncthreads();

        bf16x8 af[4], bfv[4];
        #pragma unroll
        for (int mi = 0; mi < 4; ++mi)
            af[mi]  = *(const bf16x8*)&As[(waveM + mi*16 + l15)*40 + quad*8];
        #pragma unroll
        for (int ni = 0; ni < 4; ++ni)
            bfv[ni] = *(const bf16x8*)&Bs[(waveN + ni*16 + l15)*40 + quad*8];
        #pragma unroll
        for (int mi = 0; mi < 4; ++mi)
            #pragma unroll
            for (int ni = 0; ni < 4; ++ni)
                acc[mi*4+ni] = __builtin_amdgcn_mfma_f32_16x16x32_bf16(
                                   af[mi], bfv[ni], acc[mi*4+ni], 0, 0, 0);
    }

    #pragma unroll
    for (int mi = 0; mi < 4; ++mi){
        #pragma unroll
        for (int ni = 0; ni < 4; ++ni){
            #pragma unroll
            for (int r = 0; r < 4; ++r){
                float v = acc[mi*4+ni][r];
                int row = blockM + waveM + mi*16 + quad*4 + r;
                int col = blockN + waveN + ni*16 + l15;
                if (MODE == 0){
                    int b = row >> 11, s2 = row & 2047;
                    int h = col >> 7,  kk = col & 127;
                    ((u16*)Cm)[(((size_t)(b*H_ + h))*S_ + s2)*DK_ + kk] = f2bf(v);
                } else if (MODE == 2){
                    int h = row >> 7,  kk = row & 127;
                    int b = col >> 11, s2 = col & 2047;
                    ((u16*)Cm)[(((size_t)(b*H_ + h))*DK_ + kk)*S_ + s2] = f2bf(v);
                } else {
                    ((float*)Cm)[(size_t)row*2048 + col] = v;
                }
            }
        }
    }
}

// In-place interleaved-pair RoPE (fallback path only). Q pre-scaled by log2(e)/sqrt(dk).
__global__ __launch_bounds__(256) void rope_kernel(u16* __restrict__ Q, u16* __restrict__ K)
{
    u16* T = blockIdx.y ? K : Q;
    const float osc = blockIdx.y ? 1.0f : 0.12751743f;  // log2(e)/sqrt(128)
    int t  = blockIdx.x * 256 + threadIdx.x;
    int i0 = (t & 15) * 4;
    int s  = (t >> 4) & 2047;
    size_t base = ((size_t)(t >> 4)) * 128 + (size_t)i0 * 2;
    uint4 v = *(const uint4*)&T[base];
    float f[8]; unpack8(v, f);
    const float nl2t = -13.287712379549449f / 64.0f;  // -log2(10000)/64
    float sf = (float)s;
    unsigned int out[4];
    #pragma unroll
    for (int p = 0; p < 4; ++p){
        float inv = exp2f((float)(i0 + p) * nl2t);
        float ang = sf * inv;
        float sn, cn;
        sincosf(ang, &sn, &cn);
        float e0 = f[2*p], e1 = f[2*p+1];
        float r0 = (e0*cn - e1*sn) * osc;
        float r1 = (e1*cn + e0*sn) * osc;
        out[p] = ((unsigned int)f2bf(r1) << 16) | (unsigned int)f2bf(r0);
    }
    uint4 ov; ov.x = out[0]; ov.y = out[1]; ov.z = out[2]; ov.w = out[3];
    *(uint4*)&T[base] = ov;
}

// MFMA flash attention (round 15): 4 waves x 16 q-rows per 64-row block, K
// double-buffered in LDS; V read DIRECTLY from global (L2-served, consumed once
// per block-step — staging it was pure LDS/occupancy cost; per-XCD V working set
// ~4MB = per-XCD L2). LDS 40 KiB -> 3-4 blocks/CU (was 2 at 72 KiB; kernel is
// occupancy/latency-bound: all pipes <45% at 19% occupancy). FIXED-C softmax
// (exact: exp2(S-16)/sum), cvt_pk P-pack, setprio.
__global__ __launch_bounds__(256, 3) void attn_mfma(
    const u16* Q, const u16* __restrict__ K,
    const u16* __restrict__ VT, u16* O)
{
    __shared__ __align__(16) u16 Ks[2][64*128];  // K tile [j][dk], chunk-swizzled (32 KiB)
    __shared__ __align__(16) u16 Ps[4][16*64];   // per-wave P [q][j], chunk-swizzled (8 KiB)

    const int tid  = threadIdx.x;
    const int bh   = blockIdx.x;
    const int qb   = (int)gridDim.y - 1 - (int)blockIdx.y;   // heavy blocks first
    const int w    = tid >> 6;
    const int lane = tid & 63;
    const int quad = lane >> 4;
    const int l15  = lane & 15;
    const int sw   = l15 & 7;
    const size_t qkb = (size_t)bh * S_ * DK_;

    const int qw = qb*64 + w*16;

    bf16x8 aq[4];
    {
        const u16* qp = &Q[qkb + (size_t)(qw + l15)*128 + quad*8];
        #pragma unroll
        for (int kt = 0; kt < 4; ++kt)
            aq[kt] = *(const bf16x8*)(qp + kt*32);
    }

    f32x4 oa[8];
    #pragma unroll
    for (int vt = 0; vt < 8; ++vt) oa[vt] = (f32x4){0.f,0.f,0.f,0.f};
    float l_i = 0.f;

    // stage K tile kb into buffer buf (issue-only)
    auto stageK = [&](int kb, int buf){
        #pragma unroll
        for (int it = 0; it < 4; ++it){
            int cc  = tid + it*256;
            int row = cc >> 4, cl = cc & 15;
            async16(&K[qkb + (size_t)(kb*64 + row)*128 + (size_t)((cl ^ (row & 7))*8)],
                    &Ks[buf][cc*8]);
        }
    };

    const int nkb = qb + 1;
    stageK(0, 0);
    __syncthreads();

    // per-lane V base: row v = vt*16 + l15 of VT [dk=128][S=2048], cols j local
    const u16* vbase = VT + qkb + (size_t)l15*2048 + quad*8;

    for (int kb = 0; kb < nkb; ++kb){
        const int cur = kb & 1;
        if (kb + 1 < nkb) stageK(kb + 1, cur ^ 1);

        const u16* ks = &Ks[cur][0];

        f32x4 s[4];
        __builtin_amdgcn_s_setprio(1);
        #pragma unroll
        for (int nt = 0; nt < 4; ++nt){
            f32x4 a = (f32x4){0.f,0.f,0.f,0.f};
            #pragma unroll
            for (int kt = 0; kt < 4; ++kt){
                bf16x8 ak = *(const bf16x8*)&ks[(nt*16 + l15)*128 + ((kt*4 + quad) ^ sw)*8];
                a = __builtin_amdgcn_mfma_f32_16x16x32_bf16(ak, aq[kt], a, 0,0,0);
            }
            s[nt] = a;
        }
        __builtin_amdgcn_s_setprio(0);

        // V fragments from global (L2): independent of softmax -> compiler hoists
        // the 16 loads above the exp2 chain, latency hides under it.
        bf16x8 bv[8][2];
        {
            const u16* vb = vbase + kb*64;
            #pragma unroll
            for (int vt = 0; vt < 8; ++vt)
                #pragma unroll
                for (int kt = 0; kt < 2; ++kt)
                    bv[vt][kt] = *(const bf16x8*)(vb + (size_t)vt*16*2048 + kt*32);
        }

        if (kb == nkb - 1){
            int qg = qw + l15;
            #pragma unroll
            for (int nt = 0; nt < 4; ++nt)
                #pragma unroll
                for (int rr = 0; rr < 4; ++rr){
                    int jg = kb*64 + nt*16 + quad*4 + rr;
                    if (jg > qg) s[nt][rr] = NEG_BIG;
                }
        }

        float ps = 0.f;
        #pragma unroll
        for (int nt = 0; nt < 4; ++nt)
            #pragma unroll
            for (int rr = 0; rr < 4; ++rr){
                float p = exp2f(s[nt][rr] - 16.0f);
                s[nt][rr] = p; ps += p;
            }
        ps += __shfl_xor(ps, 16, 64);
        ps += __shfl_xor(ps, 32, 64);
        l_i += ps;

        u16* pw = Ps[w];
        #pragma unroll
        for (int nt = 0; nt < 4; ++nt){
            uint2 pk;
            asm("v_cvt_pk_bf16_f32 %0, %1, %2" : "=v"(pk.x) : "v"(s[nt][0]), "v"(s[nt][1]));
            asm("v_cvt_pk_bf16_f32 %0, %1, %2" : "=v"(pk.y) : "v"(s[nt][2]), "v"(s[nt][3]));
            int c = (nt*2 + (quad >> 1)) ^ sw;
            *(uint2*)&pw[l15*64 + c*8 + (quad & 1)*4] = pk;
        }

        bf16x8 pa[2];
        #pragma unroll
        for (int kt = 0; kt < 2; ++kt)
            pa[kt] = *(const bf16x8*)&pw[l15*64 + ((kt*4 + quad) ^ sw)*8];

        __builtin_amdgcn_s_setprio(1);
        #pragma unroll
        for (int vt = 0; vt < 8; ++vt)
            #pragma unroll
            for (int kt = 0; kt < 2; ++kt)
                oa[vt] = __builtin_amdgcn_mfma_f32_16x16x32_bf16(pa[kt], bv[vt][kt], oa[vt], 0,0,0);
        __builtin_amdgcn_s_setprio(0);

        __syncthreads();
    }

    #pragma unroll
    for (int rr = 0; rr < 4; ++rr){
        float lv = __shfl(l_i, (lane & 48) | (quad*4 + rr), 64);
        float inv = 1.f / lv;
        int qg = qw + quad*4 + rr;
        #pragma unroll
        for (int vt = 0; vt < 8; ++vt)
            O[qkb + (size_t)qg*128 + vt*16 + l15] = f2bf(oa[vt][rr] * inv);
    }
}

extern "C" void kernel_launch(void* const* d_in, const int* in_sizes, int n_in,
                              void* d_out, int out_size, void* d_ws, size_t ws_size,
                              hipStream_t stream)
{
    const float* x  = (const float*)d_in[0];
    const float* wq = (const float*)d_in[1];
    const float* wk = (const float*)d_in[2];
    const float* wv = (const float*)d_in[3];
    const float* wo = (const float*)d_in[4];
    float* out = (float*)d_out;

    const size_t NT = (size_t)B_ * H_ * S_ * DK_;   // 8388608 elems (16 MiB bf16)
    const size_t NW = (size_t)D_ * D_;              // 4194304 elems (8 MiB bf16)

    if (ws_size >= (size_t)50331648){
        u16* Qw  = (u16*)d_ws;
        u16* Kw  = Qw + NT;
        u16* wvb = Qw + 2*NT;
        u16* wob = wvb + NW;
        u16* xb  = (u16*)d_out;
        u16* wqb = xb + NT;
        u16* wkb = wqb + NW;
        u16* VT  = xb + NT;
        u16* Ow  = Qw;

        cvt_all<<<dim3(12288), 256, 0, stream>>>(x, wq, wk, wv, wo,
                                                 xb, wqb, wkb, wvb, wob);
        gemm4ph<<<dim3(8, 16, 2), 512, 0, stream>>>(xb, wqb, wkb, Qw, Kw);   // + fused RoPE
        gemm256<2,2><<<dim3(32, 8, 1), 512, 0, stream>>>(wvb, xb, nullptr, VT, nullptr);
        attn_mfma<<<dim3(32, 32), 256, 0, stream>>>(Qw, Kw, VT, Ow);
        gemm256<1,2><<<dim3(16, 16, 1), 512, 0, stream>>>(Ow, wob, nullptr, out, nullptr);
    } else {
        u16* Qw  = (u16*)d_ws;
        u16* Vtd = (u16*)d_out;
        u16* Kw  = (u16*)d_out + NT;
        u16* Ow  = Qw;
        gemm_bt<0><<<dim3(16, 32, 2), 256, 0, stream>>>(x, wq, wk, Qw, Kw);
        gemm_bt<2><<<dim3(32, 16, 1), 256, 0, stream>>>(wv, x, nullptr, Vtd, nullptr);
        rope_kernel<<<dim3(4096, 2), 256, 0, stream>>>(Qw, Kw);
        attn_mfma<<<dim3(32, 32), 256, 0, stream>>>(Qw, Kw, Vtd, Ow);
        gemm_bt<1><<<dim3(16, 32, 1), 256, 0, stream>>>(Ow, wo, nullptr, out, nullptr);
    }
}

// Round 10
// 336.107 us; speedup vs baseline: 1.2505x; 1.2505x over previous
//
#include <hip/hip_runtime.h>
#include <hip/hip_bf16.h>

#define B_  2
#define S_  2048
#define D_  2048
#define H_  16
#define DK_ 128
#define M_  (B_*S_)   // 4096

typedef unsigned short u16;
typedef short bf16x8 __attribute__((ext_vector_type(8)));
typedef float f32x4  __attribute__((ext_vector_type(4)));

#define NEG_BIG (-1.0e30f)

// round-to-nearest-even fp32 -> bf16 (finite inputs)
__device__ __forceinline__ u16 f2bf(float f){
    unsigned int u = __float_as_uint(f);
    unsigned int r = (u + 0x7fffu + ((u >> 16) & 1u)) >> 16;
    return (u16)r;
}

// load 8 consecutive f32, convert to 8 bf16 packed in a uint4
__device__ __forceinline__ uint4 cvt8(const float* p){
    float4 a = *(const float4*)p;
    float4 b = *(const float4*)(p + 4);
    uint4 r;
    r.x = ((unsigned int)f2bf(a.y) << 16) | (unsigned int)f2bf(a.x);
    r.y = ((unsigned int)f2bf(a.w) << 16) | (unsigned int)f2bf(a.z);
    r.z = ((unsigned int)f2bf(b.y) << 16) | (unsigned int)f2bf(b.x);
    r.w = ((unsigned int)f2bf(b.w) << 16) | (unsigned int)f2bf(b.z);
    return r;
}

// unpack 8 bf16 (uint4) -> 8 f32
__device__ __forceinline__ void unpack8(const uint4 v, float* f){
    f[0]=__uint_as_float(v.x<<16); f[1]=__uint_as_float(v.x&0xffff0000u);
    f[2]=__uint_as_float(v.y<<16); f[3]=__uint_as_float(v.y&0xffff0000u);
    f[4]=__uint_as_float(v.z<<16); f[5]=__uint_as_float(v.z&0xffff0000u);
    f[6]=__uint_as_float(v.w<<16); f[7]=__uint_as_float(v.w&0xffff0000u);
}

// async 16B global -> LDS (gfx950). LDS dest must be wave-uniform base + lane*16.
__device__ __forceinline__ void async16(const void* g, void* l){
    __builtin_amdgcn_global_load_lds(
        (const __attribute__((address_space(1))) void*)g,
        (__attribute__((address_space(3))) void*)l, 16, 0, 0);
}

// ---------------- one-shot f32 -> bf16 conversion of all inputs ----------------
__global__ __launch_bounds__(256) void cvt_all(
    const float* __restrict__ x,  const float* __restrict__ wq, const float* __restrict__ wk,
    const float* __restrict__ wv, const float* __restrict__ wo,
    u16* __restrict__ xb, u16* __restrict__ wqb, u16* __restrict__ wkb,
    u16* __restrict__ wvb, u16* __restrict__ wob)
{
    int c = blockIdx.x*256 + threadIdx.x;
    const float* src; u16* dst; int lc;
    if      (c < 1048576){ src = x;  dst = xb;  lc = c; }
    else if (c < 1572864){ src = wq; dst = wqb; lc = c - 1048576; }
    else if (c < 2097152){ src = wk; dst = wkb; lc = c - 1572864; }
    else if (c < 2621440){ src = wv; dst = wvb; lc = c - 2097152; }
    else                 { src = wo; dst = wob; lc = c - 2621440; }
    *(uint4*)&dst[(size_t)lc*8] = cvt8(&src[(size_t)lc*8]);
}

// ---------------- 256^2 4-phase bf16 GEMM for QK-proj (round-8 validated) ----------------
// + RoPE fused into the epilogue (round-9 validated: rotation partner kk^1 lives
// in lane l15^1 -> one shfl_xor + sincos per element; Q pre-scaled by
// log2(e)/sqrt(dk) for exp2-domain softmax).
__global__ __launch_bounds__(512, 2) void gemm4ph(
    const u16* __restrict__ A, const u16* __restrict__ W0, const u16* __restrict__ W1,
    u16* __restrict__ C0, u16* __restrict__ C1)
{
    __shared__ __align__(16) u16 Ab[2][256*64];   // [buf][row][col], XOR-chunk phys layout
    __shared__ __align__(16) u16 Bb[2][256*64];

    const int tid  = threadIdx.x;
    const int lane = tid & 63;
    const int w    = tid >> 6;
    const int quad = lane >> 4;
    const int l15  = lane & 15;
    const int wM   = w & 1;           // A-half this wave consumes
    const int wN   = w >> 1;          // 0..3 (n-quarter)
    const int bH   = w >> 2;          // B-half this wave consumes
    const int cw   = w >> 1;          // coop index among same-wM waves (0..3)
    const int cb   = w & 3;           // coop index among same-bH waves (0..3)
    const int sw   = l15 & 7;
    const int blockN = blockIdx.x * 256;
    const int blockM = blockIdx.y * 256;

    const u16* Wm = blockIdx.z ? W1 : W0;
    u16*       Cm = blockIdx.z ? C1 : C0;

    f32x4 acc[32];                    // [mi 0..7][ni 0..3]
    #pragma unroll
    for (int i = 0; i < 32; ++i) acc[i] = (f32x4){0.f,0.f,0.f,0.f};

    // stage load l (0..3) of my A-half of tile t into Ab[t&1]
    auto stageA = [&](int t, int l){
        int c  = l*256 + cw*64 + lane;        // chunk in half, rows in consumption order
        int ra = c >> 3, g = c & 7;
        int cl = g ^ (ra & 7);                // inverse XOR swizzle on global source
        int kb = t*64 + cl*8;
        async16(&A[(size_t)(blockM + wM*128 + ra)*2048 + kb],
                &Ab[t & 1][wM*8192 + c*8]);
    };
    auto stageB = [&](int t, int l){
        int c  = l*256 + cb*64 + lane;
        int rb = c >> 3, g = c & 7;
        int cl = g ^ (rb & 7);
        int kb = t*64 + cl*8;
        async16(&Wm[(size_t)(blockN + bH*128 + rb)*2048 + kb],
                &Bb[t & 1][bH*8192 + c*8]);
    };

    // prologue: B(0) then A(0); retire B(0)+A(0)rows0-63 (first 6), leave A(0) tail
    stageB(0,0); stageB(0,1); stageB(0,2); stageB(0,3);
    stageA(0,0); stageA(0,1); stageA(0,2); stageA(0,3);
    asm volatile("s_waitcnt vmcnt(2)" ::: "memory");
    __builtin_amdgcn_s_barrier();
    __builtin_amdgcn_sched_barrier(0);

    for (int t = 0; t < 32; ++t){
        const u16* ab = &Ab[t & 1][0];
        const u16* bb = &Bb[t & 1][0];
        const bool st = (t < 31);
        bf16x8 bfv[4][2], af[2][2];

        // ---- phase 0: mi 0,1 (+ load all B-frags into regs) ----
        #pragma unroll
        for (int ni = 0; ni < 4; ++ni)
            #pragma unroll
            for (int kk = 0; kk < 2; ++kk)
                bfv[ni][kk] = *(const bf16x8*)&bb[(wN*64 + ni*16 + l15)*64 + (((kk*4+quad) ^ sw))*8];
        #pragma unroll
        for (int j = 0; j < 2; ++j)
            #pragma unroll
            for (int kk = 0; kk < 2; ++kk)
                af[j][kk] = *(const bf16x8*)&ab[(wM*128 + (0+j)*16 + l15)*64 + (((kk*4+quad) ^ sw))*8];
        if (st){ stageB(t+1, 0); stageB(t+1, 1); }
        __builtin_amdgcn_s_barrier();
        asm volatile("s_waitcnt lgkmcnt(0)" ::: "memory");
        __builtin_amdgcn_sched_barrier(0);
        __builtin_amdgcn_s_setprio(1);
        #pragma unroll
        for (int j = 0; j < 2; ++j)
            #pragma unroll
            for (int ni = 0; ni < 4; ++ni)
                #pragma unroll
                for (int kk = 0; kk < 2; ++kk)
                    acc[(0+j)*4 + ni] = __builtin_amdgcn_mfma_f32_16x16x32_bf16(
                        af[j][kk], bfv[ni][kk], acc[(0+j)*4 + ni], 0, 0, 0);
        __builtin_amdgcn_s_setprio(0);
        __builtin_amdgcn_s_barrier();
        __builtin_amdgcn_sched_barrier(0);

        // ---- phase 1: mi 2,3 ----
        #pragma unroll
        for (int j = 0; j < 2; ++j)
            #pragma unroll
            for (int kk = 0; kk < 2; ++kk)
                af[j][kk] = *(const bf16x8*)&ab[(wM*128 + (2+j)*16 + l15)*64 + (((kk*4+quad) ^ sw))*8];
        if (st){ stageB(t+1, 2); stageB(t+1, 3); }
        __builtin_amdgcn_s_barrier();
        asm volatile("s_waitcnt lgkmcnt(0)" ::: "memory");
        __builtin_amdgcn_sched_barrier(0);
        __builtin_amdgcn_s_setprio(1);
        #pragma unroll
        for (int j = 0; j < 2; ++j)
            #pragma unroll
            for (int ni = 0; ni < 4; ++ni)
                #pragma unroll
                for (int kk = 0; kk < 2; ++kk)
                    acc[(2+j)*4 + ni] = __builtin_amdgcn_mfma_f32_16x16x32_bf16(
                        af[j][kk], bfv[ni][kk], acc[(2+j)*4 + ni], 0, 0, 0);
        __builtin_amdgcn_s_setprio(0);
        if (st) { asm volatile("s_waitcnt vmcnt(4)" ::: "memory"); }   // A(t) rows 64-127 land
        else    { asm volatile("s_waitcnt vmcnt(0)" ::: "memory"); }
        __builtin_amdgcn_s_barrier();
        __builtin_amdgcn_sched_barrier(0);

        // ---- phase 2: mi 4,5 ----
        #pragma unroll
        for (int j = 0; j < 2; ++j)
            #pragma unroll
            for (int kk = 0; kk < 2; ++kk)
                af[j][kk] = *(const bf16x8*)&ab[(wM*128 + (4+j)*16 + l15)*64 + (((kk*4+quad) ^ sw))*8];
        if (st){ stageA(t+1, 0); stageA(t+1, 1); }
        __builtin_amdgcn_s_barrier();
        asm volatile("s_waitcnt lgkmcnt(0)" ::: "memory");
        __builtin_amdgcn_sched_barrier(0);
        __builtin_amdgcn_s_setprio(1);
        #pragma unroll
        for (int j = 0; j < 2; ++j)
            #pragma unroll
            for (int ni = 0; ni < 4; ++ni)
                #pragma unroll
                for (int kk = 0; kk < 2; ++kk)
                    acc[(4+j)*4 + ni] = __builtin_amdgcn_mfma_f32_16x16x32_bf16(
                        af[j][kk], bfv[ni][kk], acc[(4+j)*4 + ni], 0, 0, 0);
        __builtin_amdgcn_s_setprio(0);
        __builtin_amdgcn_s_barrier();
        __builtin_amdgcn_sched_barrier(0);

        // ---- phase 3: mi 6,7 ----
        #pragma unroll
        for (int j = 0; j < 2; ++j)
            #pragma unroll
            for (int kk = 0; kk < 2; ++kk)
                af[j][kk] = *(const bf16x8*)&ab[(wM*128 + (6+j)*16 + l15)*64 + (((kk*4+quad) ^ sw))*8];
        if (st){ stageA(t+1, 2); stageA(t+1, 3); }
        __builtin_amdgcn_s_barrier();
        asm volatile("s_waitcnt lgkmcnt(0)" ::: "memory");
        __builtin_amdgcn_sched_barrier(0);
        __builtin_amdgcn_s_setprio(1);
        #pragma unroll
        for (int j = 0; j < 2; ++j)
            #pragma unroll
            for (int ni = 0; ni < 4; ++ni)
                #pragma unroll
                for (int kk = 0; kk < 2; ++kk)
                    acc[(6+j)*4 + ni] = __builtin_amdgcn_mfma_f32_16x16x32_bf16(
                        af[j][kk], bfv[ni][kk], acc[(6+j)*4 + ni], 0, 0, 0);
        __builtin_amdgcn_s_setprio(0);
        if (st) { asm volatile("s_waitcnt vmcnt(2)" ::: "memory"); }   // B(t+1)+A(t+1)head land
        __builtin_amdgcn_s_barrier();
        __builtin_amdgcn_sched_barrier(0);
    }

    // epilogue: fused interleaved-pair RoPE + write C [b][h][s][dk].
    // Pair partner kk^1 is in lane l15^1 (same quad/ni/r). Q (z=0) pre-scaled.
    const float osc  = blockIdx.z ? 1.0f : 0.12751743f;   // log2(e)/sqrt(128)
    const float nl2t = -13.287712379549449f / 64.0f;      // -log2(10000)/64
    #pragma unroll
    for (int mi = 0; mi < 8; ++mi){
        #pragma unroll
        for (int ni = 0; ni < 4; ++ni){
            #pragma unroll
            for (int r = 0; r < 4; ++r){
                float v = acc[mi*4 + ni][r];
                int row = blockM + wM*128 + mi*16 + quad*4 + r;
                int col = blockN + wN*64 + ni*16 + l15;
                float pv = __shfl_xor(v, 1, 64);          // partner kk^1
                int ii = (col >> 1) & 63;                 // rotary pair index
                float inv = exp2f((float)ii * nl2t);
                float ang = (float)(row & 2047) * inv;
                float sn, cn; __sincosf(ang, &sn, &cn);
                float rv = ((col & 1) ? (v*cn + pv*sn) : (v*cn - pv*sn)) * osc;
                int b = row >> 11, s2 = row & 2047;
                int h = col >> 7,  kk = col & 127;
                Cm[(((size_t)(b*H_ + h))*S_ + s2)*DK_ + kk] = f2bf(rv);
            }
        }
    }
}

// ---------------- 256xBN 4-slot-ring bf16 GEMM (round-6 validated) ----------------
template<int MODE, int NF>
__global__ __launch_bounds__(512, 2) void gemm256(
    const u16* __restrict__ A, const u16* __restrict__ W0, const u16* __restrict__ W1,
    void* __restrict__ C0, void* __restrict__ C1)
{
    constexpr int BN = NF * 64;
    __shared__ __align__(16) u16 ring[4][(256 + BN) * 32];

    const int tid  = threadIdx.x;
    const int lane = tid & 63;
    const int w    = tid >> 6;
    const int quad = lane >> 4;
    const int l15  = lane & 15;
    const int wM   = w & 1;
    const int wN   = w >> 1;
    const int blockN = blockIdx.x * BN;
    const int blockM = blockIdx.y * 256;

    const u16* Wm; void* Cm;
    if (MODE == 0){ Wm = blockIdx.z ? W1 : W0; Cm = blockIdx.z ? (void*)C1 : (void*)C0; }
    else          { Wm = W0; Cm = C0; }

    const int cswz = quad ^ ((l15 >> 1) & 3);

    f32x4 acc[8 * NF];
    #pragma unroll
    for (int i = 0; i < 8 * NF; ++i) acc[i] = (f32x4){0.f,0.f,0.f,0.f};

    auto stage = [&](int t){
        const int k0 = t * 32;
        u16* la = (u16*)&ring[t & 3][0];
        u16* lb = la + 256*32;
        #pragma unroll
        for (int it = 0; it < 2; ++it){
            int cc  = it*512 + tid;
            int row = cc >> 2;
            int g   = (cc & 3) ^ ((cc >> 3) & 3);
            int kb  = k0 + g*8;
            const u16* ga;
            if (MODE == 1){
                int rg = blockM + row;
                int b = rg >> 11, s2 = rg & 2047;
                int h = kb >> 7,  kk = kb & 127;
                ga = &A[(((size_t)(b*H_ + h))*S_ + s2)*DK_ + kk];
            } else {
                ga = &A[(size_t)(blockM + row)*2048 + kb];
            }
            async16(ga, la + cc*8);
        }
        #pragma unroll
        for (int it = 0; it < BN/128; ++it){
            int cc  = it*512 + tid;
            int row = cc >> 2;
            int g   = (cc & 3) ^ ((cc >> 3) & 3);
            int kb  = k0 + g*8;
            async16(&Wm[(size_t)(blockN + row)*2048 + kb], lb + cc*8);
        }
    };

    stage(0); stage(1); stage(2);
    if constexpr (NF == 4) asm volatile("s_waitcnt vmcnt(8)" ::: "memory");
    else                   asm volatile("s_waitcnt vmcnt(6)" ::: "memory");
    __builtin_amdgcn_s_barrier();
    __builtin_amdgcn_sched_barrier(0);

    for (int t = 0; t < 64; ++t){
        const u16* la = (const u16*)&ring[t & 3][0];
        const u16* lb = la + 256*32;

        if (t <= 60) stage(t + 3);

        bf16x8 bfv[NF];
        #pragma unroll
        for (int ni = 0; ni < NF; ++ni)
            bfv[ni] = *(const bf16x8*)&lb[(wN*(NF*16) + ni*16 + l15)*32 + cswz*8];

        #pragma unroll
        for (int hf = 0; hf < 2; ++hf){
            bf16x8 af[4];
            #pragma unroll
            for (int mi = 0; mi < 4; ++mi)
                af[mi] = *(const bf16x8*)&la[(wM*128 + hf*64 + mi*16 + l15)*32 + cswz*8];
            __builtin_amdgcn_s_setprio(1);
            #pragma unroll
            for (int mi = 0; mi < 4; ++mi)
                #pragma unroll
                for (int ni = 0; ni < NF; ++ni)
                    acc[(hf*4 + mi)*NF + ni] = __builtin_amdgcn_mfma_f32_16x16x32_bf16(
                        af[mi], bfv[ni], acc[(hf*4 + mi)*NF + ni], 0, 0, 0);
            __builtin_amdgcn_s_setprio(0);
        }

        if constexpr (NF == 4){
            if (t <= 60)      { asm volatile("s_waitcnt vmcnt(8)" ::: "memory"); }
            else if (t == 61) { asm volatile("s_waitcnt vmcnt(4)" ::: "memory"); }
            else if (t == 62) { asm volatile("s_waitcnt vmcnt(0)" ::: "memory"); }
        } else {
            if (t <= 60)      { asm volatile("s_waitcnt vmcnt(6)" ::: "memory"); }
            else if (t == 61) { asm volatile("s_waitcnt vmcnt(3)" ::: "memory"); }
            else if (t == 62) { asm volatile("s_waitcnt vmcnt(0)" ::: "memory"); }
        }
        __builtin_amdgcn_s_barrier();
        __builtin_amdgcn_sched_barrier(0);
    }

    #pragma unroll
    for (int hf = 0; hf < 2; ++hf){
        #pragma unroll
        for (int mi = 0; mi < 4; ++mi){
            #pragma unroll
            for (int ni = 0; ni < NF; ++ni){
                #pragma unroll
                for (int r = 0; r < 4; ++r){
                    float v = acc[(hf*4 + mi)*NF + ni][r];
                    int row = blockM + wM*128 + hf*64 + mi*16 + quad*4 + r;
                    int col = blockN + wN*(NF*16) + ni*16 + l15;
                    if (MODE == 0){
                        int b = row >> 11, s2 = row & 2047;
                        int h = col >> 7,  kk = col & 127;
                        ((u16*)Cm)[(((size_t)(b*H_ + h))*S_ + s2)*DK_ + kk] = f2bf(v);
                    } else if (MODE == 2){
                        int h = row >> 7,  kk = row & 127;
                        int b = col >> 11, s2 = col & 2047;
                        ((u16*)Cm)[(((size_t)(b*H_ + h))*DK_ + kk)*S_ + s2] = f2bf(v);
                    } else {
                        ((float*)Cm)[(size_t)row*2048 + col] = v;
                    }
                }
            }
        }
    }
}

// ---------------- fallback mixed GEMM (round-4, validated) ----------------
template<int MODE>
__global__ __launch_bounds__(256) void gemm_bt(
    const void* __restrict__ Av,
    const float* __restrict__ W0, const float* __restrict__ W1,
    void* __restrict__ C0, void* __restrict__ C1)
{
    __shared__ u16 As[128*40];
    __shared__ u16 Bs[128*40];

    const int tid  = threadIdx.x;
    const int lane = tid & 63;
    const int w    = tid >> 6;
    const int quad = lane >> 4;
    const int l15  = lane & 15;
    const int blockN = blockIdx.x * 128;
    const int blockM = blockIdx.y * 128;

    const float* Wm; void* Cm;
    if (MODE == 0){ Wm = blockIdx.z ? W1 : W0; Cm = blockIdx.z ? (void*)C1 : (void*)C0; }
    else          { Wm = W0; Cm = C0; }

    const int waveM = (w & 1) * 64;
    const int waveN = (w >> 1) * 64;

    f32x4 acc[16];
    #pragma unroll
    for (int i = 0; i < 16; ++i) acc[i] = (f32x4){0.f,0.f,0.f,0.f};

    for (int k0 = 0; k0 < 2048; k0 += 32){
        __syncthreads();
        #pragma unroll
        for (int it = 0; it < 2; ++it){
            int cc  = tid + it*256;
            int row = cc >> 2;
            int ch  = cc & 3;
            int kb  = k0 + ch*8;
            uint4 va;
            if (MODE == 1){
                int g = blockM + row;
                int b = g >> 11, s2 = g & 2047;
                int h = kb >> 7, kk = kb & 127;
                va = *(const uint4*)&((const u16*)Av)[(((size_t)(b*H_ + h))*S_ + s2)*DK_ + kk];
            } else {
                va = cvt8(&((const float*)Av)[(size_t)(blockM+row)*2048 + kb]);
            }
            uint4 vb = cvt8(&Wm[(size_t)(blockN+row)*2048 + kb]);
            *(uint4*)&As[row*40 + ch*8] = va;
            *(uint4*)&Bs[row*40 + ch*8] = vb;
        }
        __syncthreads();

        bf16x8 af[4], bfv[4];
        #pragma unroll
        for (int mi = 0; mi < 4; ++mi)
            af[mi]  = *(const bf16x8*)&As[(waveM + mi*16 + l15)*40 + quad*8];
        #pragma unroll
        for (int ni = 0; ni < 4; ++ni)
            bfv[ni] = *(const bf16x8*)&Bs[(waveN + ni*16 + l15)*40 + quad*8];
        #pragma unroll
        for (int mi = 0; mi < 4; ++mi)
            #pragma unroll
            for (int ni = 0; ni < 4; ++ni)
                acc[mi*4+ni] = __builtin_amdgcn_mfma_f32_16x16x32_bf16(
                                   af[mi], bfv[ni], acc[mi*4+ni], 0, 0, 0);
    }

    #pragma unroll
    for (int mi = 0; mi < 4; ++mi){
        #pragma unroll
        for (int ni = 0; ni < 4; ++ni){
            #pragma unroll
            for (int r = 0; r < 4; ++r){
                float v = acc[mi*4+ni][r];
                int row = blockM + waveM + mi*16 + quad*4 + r;
                int col = blockN + waveN + ni*16 + l15;
                if (MODE == 0){
                    int b = row >> 11, s2 = row & 2047;
                    int h = col >> 7,  kk = col & 127;
                    ((u16*)Cm)[(((size_t)(b*H_ + h))*S_ + s2)*DK_ + kk] = f2bf(v);
                } else if (MODE == 2){
                    int h = row >> 7,  kk = row & 127;
                    int b = col >> 11, s2 = col & 2047;
                    ((u16*)Cm)[(((size_t)(b*H_ + h))*DK_ + kk)*S_ + s2] = f2bf(v);
                } else {
                    ((float*)Cm)[(size_t)row*2048 + col] = v;
                }
            }
        }
    }
}

// In-place interleaved-pair RoPE (fallback path only). Q pre-scaled by log2(e)/sqrt(dk).
__global__ __launch_bounds__(256) void rope_kernel(u16* __restrict__ Q, u16* __restrict__ K)
{
    u16* T = blockIdx.y ? K : Q;
    const float osc = blockIdx.y ? 1.0f : 0.12751743f;  // log2(e)/sqrt(128)
    int t  = blockIdx.x * 256 + threadIdx.x;
    int i0 = (t & 15) * 4;
    int s  = (t >> 4) & 2047;
    size_t base = ((size_t)(t >> 4)) * 128 + (size_t)i0 * 2;
    uint4 v = *(const uint4*)&T[base];
    float f[8]; unpack8(v, f);
    const float nl2t = -13.287712379549449f / 64.0f;  // -log2(10000)/64
    float sf = (float)s;
    unsigned int out[4];
    #pragma unroll
    for (int p = 0; p < 4; ++p){
        float inv = exp2f((float)(i0 + p) * nl2t);
        float ang = sf * inv;
        float sn, cn;
        sincosf(ang, &sn, &cn);
        float e0 = f[2*p], e1 = f[2*p+1];
        float r0 = (e0*cn - e1*sn) * osc;
        float r1 = (e1*cn + e0*sn) * osc;
        out[p] = ((unsigned int)f2bf(r1) << 16) | (unsigned int)f2bf(r0);
    }
    uint4 ov; ov.x = out[0]; ov.y = out[1]; ov.z = out[2]; ov.w = out[3];
    *(uint4*)&T[base] = ov;
}

// MFMA flash attention (round-8 validated config, reverted from R9's V-from-global
// regression: V loads on the critical path doubled dur; V must be LDS-prefetched
// one iteration ahead). 4 waves x 16 q-rows per 64-row block, K+V double-buffered
// via global_load_lds, FIXED-C softmax (exact: exp2(S-16)/sum), cvt_pk P-pack,
// setprio.
__global__ __launch_bounds__(256, 4) void attn_mfma(
    const u16* Q, const u16* __restrict__ K,
    const u16* __restrict__ VT, u16* O)
{
    __shared__ __align__(16) u16 Ks[2][64*128];
    __shared__ __align__(16) u16 Vs[2][128*64];
    __shared__ __align__(16) u16 Ps[4][16*64];

    const int tid  = threadIdx.x;
    const int bh   = blockIdx.x;
    const int qb   = (int)gridDim.y - 1 - (int)blockIdx.y;   // heavy blocks first
    const int w    = tid >> 6;
    const int lane = tid & 63;
    const int quad = lane >> 4;
    const int l15  = lane & 15;
    const int sw   = l15 & 7;
    const size_t qkb = (size_t)bh * S_ * DK_;

    const int qw = qb*64 + w*16;

    bf16x8 aq[4];
    {
        const u16* qp = &Q[qkb + (size_t)(qw + l15)*128 + quad*8];
        #pragma unroll
        for (int kt = 0; kt < 4; ++kt)
            aq[kt] = *(const bf16x8*)(qp + kt*32);
    }

    f32x4 oa[8];
    #pragma unroll
    for (int vt = 0; vt < 8; ++vt) oa[vt] = (f32x4){0.f,0.f,0.f,0.f};
    float l_i = 0.f;

    auto stage = [&](int kb, int buf){
        #pragma unroll
        for (int it = 0; it < 4; ++it){
            int cc  = tid + it*256;
            int row = cc >> 4, cl = cc & 15;
            async16(&K[qkb + (size_t)(kb*64 + row)*128 + (size_t)((cl ^ (row & 7))*8)],
                    &Ks[buf][cc*8]);
        }
        #pragma unroll
        for (int it = 0; it < 4; ++it){
            int cc  = tid + it*256;
            int row = cc >> 3, cl = cc & 7;
            async16(&VT[qkb + (size_t)row*S_ + (size_t)(kb*64 + (cl ^ (row & 7))*8)],
                    &Vs[buf][cc*8]);
        }
    };

    const int nkb = qb + 1;
    stage(0, 0);
    __syncthreads();

    for (int kb = 0; kb < nkb; ++kb){
        const int cur = kb & 1;
        if (kb + 1 < nkb) stage(kb + 1, cur ^ 1);

        const u16* ks = &Ks[cur][0];
        const u16* vs = &Vs[cur][0];

        f32x4 s[4];
        __builtin_amdgcn_s_setprio(1);
        #pragma unroll
        for (int nt = 0; nt < 4; ++nt){
            f32x4 a = (f32x4){0.f,0.f,0.f,0.f};
            #pragma unroll
            for (int kt = 0; kt < 4; ++kt){
                bf16x8 ak = *(const bf16x8*)&ks[(nt*16 + l15)*128 + ((kt*4 + quad) ^ sw)*8];
                a = __builtin_amdgcn_mfma_f32_16x16x32_bf16(ak, aq[kt], a, 0,0,0);
            }
            s[nt] = a;
        }
        __builtin_amdgcn_s_setprio(0);

        if (kb == nkb - 1){
            int qg = qw + l15;
            #pragma unroll
            for (int nt = 0; nt < 4; ++nt)
                #pragma unroll
                for (int rr = 0; rr < 4; ++rr){
                    int jg = kb*64 + nt*16 + quad*4 + rr;
                    if (jg > qg) s[nt][rr] = NEG_BIG;
                }
        }

        float ps = 0.f;
        #pragma unroll
        for (int nt = 0; nt < 4; ++nt)
            #pragma unroll
            for (int rr = 0; rr < 4; ++rr){
                float p = exp2f(s[nt][rr] - 16.0f);
                s[nt][rr] = p; ps += p;
            }
        ps += __shfl_xor(ps, 16, 64);
        ps += __shfl_xor(ps, 32, 64);
        l_i += ps;

        u16* pw = Ps[w];
        #pragma unroll
        for (int nt = 0; nt < 4; ++nt){
            uint2 pk;
            asm("v_cvt_pk_bf16_f32 %0, %1, %2" : "=v"(pk.x) : "v"(s[nt][0]), "v"(s[nt][1]));
            asm("v_cvt_pk_bf16_f32 %0, %1, %2" : "=v"(pk.y) : "v"(s[nt][2]), "v"(s[nt][3]));
            int c = (nt*2 + (quad >> 1)) ^ sw;
            *(uint2*)&pw[l15*64 + c*8 + (quad & 1)*4] = pk;
        }

        bf16x8 pa[2];
        #pragma unroll
        for (int kt = 0; kt < 2; ++kt)
            pa[kt] = *(const bf16x8*)&pw[l15*64 + ((kt*4 + quad) ^ sw)*8];

        __builtin_amdgcn_s_setprio(1);
        #pragma unroll
        for (int vt = 0; vt < 8; ++vt){
            #pragma unroll
            for (int kt = 0; kt < 2; ++kt){
                bf16x8 bv = *(const bf16x8*)&vs[(vt*16 + l15)*64 + ((kt*4 + quad) ^ sw)*8];
                oa[vt] = __builtin_amdgcn_mfma_f32_16x16x32_bf16(pa[kt], bv, oa[vt], 0,0,0);
            }
        }
        __builtin_amdgcn_s_setprio(0);

        __syncthreads();
    }

    #pragma unroll
    for (int rr = 0; rr < 4; ++rr){
        float lv = __shfl(l_i, (lane & 48) | (quad*4 + rr), 64);
        float inv = 1.f / lv;
        int qg = qw + quad*4 + rr;
        #pragma unroll
        for (int vt = 0; vt < 8; ++vt)
            O[qkb + (size_t)qg*128 + vt*16 + l15] = f2bf(oa[vt][rr] * inv);
    }
}

extern "C" void kernel_launch(void* const* d_in, const int* in_sizes, int n_in,
                              void* d_out, int out_size, void* d_ws, size_t ws_size,
                              hipStream_t stream)
{
    const float* x  = (const float*)d_in[0];
    const float* wq = (const float*)d_in[1];
    const float* wk = (const float*)d_in[2];
    const float* wv = (const float*)d_in[3];
    const float* wo = (const float*)d_in[4];
    float* out = (float*)d_out;

    const size_t NT = (size_t)B_ * H_ * S_ * DK_;   // 8388608 elems (16 MiB bf16)
    const size_t NW = (size_t)D_ * D_;              // 4194304 elems (8 MiB bf16)

    if (ws_size >= (size_t)50331648){
        u16* Qw  = (u16*)d_ws;
        u16* Kw  = Qw + NT;
        u16* wvb = Qw + 2*NT;
        u16* wob = wvb + NW;
        u16* xb  = (u16*)d_out;
        u16* wqb = xb + NT;
        u16* wkb = wqb + NW;
        u16* VT  = xb + NT;
        u16* Ow  = Qw;

        cvt_all<<<dim3(12288), 256, 0, stream>>>(x, wq, wk, wv, wo,
                                                 xb, wqb, wkb, wvb, wob);
        gemm4ph<<<dim3(8, 16, 2), 512, 0, stream>>>(xb, wqb, wkb, Qw, Kw);   // + fused RoPE
        gemm256<2,2><<<dim3(32, 8, 1), 512, 0, stream>>>(wvb, xb, nullptr, VT, nullptr);
        attn_mfma<<<dim3(32, 32), 256, 0, stream>>>(Qw, Kw, VT, Ow);
        gemm256<1,2><<<dim3(16, 16, 1), 512, 0, stream>>>(Ow, wob, nullptr, out, nullptr);
    } else {
        u16* Qw  = (u16*)d_ws;
        u16* Vtd = (u16*)d_out;
        u16* Kw  = (u16*)d_out + NT;
        u16* Ow  = Qw;
        gemm_bt<0><<<dim3(16, 32, 2), 256, 0, stream>>>(x, wq, wk, Qw, Kw);
        gemm_bt<2><<<dim3(32, 16, 1), 256, 0, stream>>>(wv, x, nullptr, Vtd, nullptr);
        rope_kernel<<<dim3(4096, 2), 256, 0, stream>>>(Qw, Kw);
        attn_mfma<<<dim3(32, 32), 256, 0, stream>>>(Qw, Kw, Vtd, Ow);
        gemm_bt<1><<<dim3(16, 32, 1), 256, 0, stream>>>(Ow, wo, nullptr, out, nullptr);
    }
}